// Round 12
// baseline (112.490 us; speedup 1.0000x reference)
//
#include <hip/hip_runtime.h>

#define EPS 1e-5f

static constexpr int D  = 128;
static constexpr int L  = 256;
static constexpr int C  = 256;
static constexpr int OC = 32;
static constexpr int PC = 256;

typedef __attribute__((ext_vector_type(8))) short bfrag8;   // 8 bf16 (4 VGPR)
typedef __attribute__((ext_vector_type(4))) short bhalf4;   // 4 bf16 (8B)
typedef __attribute__((ext_vector_type(4))) float f32x4;
typedef __attribute__((ext_vector_type(4))) unsigned int u32x4;

__device__ inline unsigned short f2bf(float f) {
  union { float f; unsigned u; } v; v.f = f;
  unsigned r = v.u + 0x7FFF + ((v.u >> 16) & 1);   // RNE
  return (unsigned short)(r >> 16);
}

// ---------------- Kernel 0: prep ----------------
// Wbf3: Wout bf16, MFMA A-fragment order (M-side = p):
//   elem ((pf*32+ks)*64+lane)*8+j = Wout[p = pf*16+(lane&15)][orig(kp)],
//   kp = ks*32+(lane>>4)*8+j; kp = q*32+c -> orig = c*32+q.   (pf 0..15)
// Wlnf: [Wl|Wr] bf16, MFMA B-fragment order (N-side = out channel).
__global__ __launch_bounds__(256)
void prep(const float* __restrict__ Wl, const float* __restrict__ Wr,
          const float* __restrict__ Wout,
          unsigned short* __restrict__ Wbf3, unsigned short* __restrict__ Wlnf) {
  const int t = threadIdx.x, b = blockIdx.x;
  {
    const int e0 = (b * 256 + t) * 4;
    const int lane = (e0 >> 3) & 63, ks = (e0 >> 9) & 31, pf = e0 >> 14;
    const int p = pf * 16 + (lane & 15);
    unsigned short v[4];
    #pragma unroll
    for (int j = 0; j < 4; ++j) {
      const int kp = ks * 32 + ((lane >> 4) * 8) + ((e0 + j) & 7);
      const int c = kp & 31, q = kp >> 5;
      v[j] = f2bf(Wout[p * 1024 + c * 32 + q]);
    }
    *(bhalf4*)(Wbf3 + e0) = *(bhalf4*)v;
  }
  if (b < 16) {
    const int e0 = (b * 256 + t) * 4;   // < 16384
    const int lane = (e0 >> 3) & 63, ks = (e0 >> 9) & 7, nf = e0 >> 12;
    const int n = nf * 16 + (lane & 15);
    unsigned short v[4];
    #pragma unroll
    for (int j = 0; j < 4; ++j) {
      const int k = ks * 32 + ((lane >> 4) * 8) + ((e0 + j) & 7);
      v[j] = f2bf(n < 32 ? Wl[n * 256 + k] : Wr[(n - 32) * 256 + k]);
    }
    *(bhalf4*)(Wlnf + e0) = *(bhalf4*)v;
  }
}

// ---------------- Kernel 1: LayerNorm + dual projection (MFMA) ----------------
__global__ __launch_bounds__(256, 4)
void ln_proj(const float* __restrict__ msa,
             const float* __restrict__ lnw, const float* __restrict__ lnb,
             const unsigned short* __restrict__ Wlnf,
             const float* __restrict__ bl, const float* __restrict__ br,
             unsigned short* __restrict__ leftT, unsigned short* __restrict__ rightT) {
  __shared__ char xb[32768];   // [64 r][256 c] bf16, swizzled ^((r&7)<<4)

  const int t = threadIdx.x, lane = t & 63, w = t >> 6;
  const int d0 = blockIdx.x * 8, l0 = blockIdx.y * 8;

  float4 xv[16];
  #pragma unroll
  for (int i = 0; i < 16; ++i) {
    const int r = i * 4 + w, dd = r & 7, ll = r >> 3;
    xv[i] = *(const float4*)(msa + ((size_t)(d0 + dd) * 256 + (l0 + ll)) * 256 + lane * 4);
  }

  float mu[16], rs[16];
  #pragma unroll
  for (int i = 0; i < 16; ++i) {
    float s  = xv[i].x + xv[i].y + xv[i].z + xv[i].w;
    float s2 = xv[i].x * xv[i].x + xv[i].y * xv[i].y + xv[i].z * xv[i].z + xv[i].w * xv[i].w;
    #pragma unroll
    for (int off = 32; off >= 1; off >>= 1) {
      s  += __shfl_xor(s, off);
      s2 += __shfl_xor(s2, off);
    }
    mu[i] = s * (1.0f / C);
    rs[i] = rsqrtf(s2 * (1.0f / C) - mu[i] * mu[i] + EPS);
  }

  {
    const float4 wv = *(const float4*)(lnw + lane * 4);
    const float4 bv = *(const float4*)(lnb + lane * 4);
    #pragma unroll
    for (int i = 0; i < 16; ++i) {
      const int r = i * 4 + w;
      float4 v = xv[i];
      unsigned short u[4];
      u[0] = f2bf((v.x - mu[i]) * rs[i] * wv.x + bv.x);
      u[1] = f2bf((v.y - mu[i]) * rs[i] * wv.y + bv.y);
      u[2] = f2bf((v.z - mu[i]) * rs[i] * wv.z + bv.z);
      u[3] = f2bf((v.w - mu[i]) * rs[i] * wv.w + bv.w);
      *(bhalf4*)&xb[r * 512 + ((lane * 8) ^ ((r & 7) << 4))] = *(bhalf4*)u;
    }
  }
  __syncthreads();

  bfrag8 wf[8];
  {
    const unsigned short* Wp = Wlnf + ((size_t)w * 8 * 64 + lane) * 8;
    #pragma unroll
    for (int ks = 0; ks < 8; ++ks) wf[ks] = *(const bfrag8*)(Wp + ks * 512);
  }
  f32x4 acc[4];
  #pragma unroll
  for (int mf = 0; mf < 4; ++mf) acc[mf] = (f32x4)0.f;
  #pragma unroll
  for (int ks = 0; ks < 8; ++ks) {
    #pragma unroll
    for (int mf = 0; mf < 4; ++mf) {
      const int row = mf * 16 + (lane & 15);
      const bfrag8 af = *(const bfrag8*)&xb[row * 512 +
                          ((ks * 64 + ((lane >> 4) << 4)) ^ ((row & 7) << 4))];
      acc[mf] = __builtin_amdgcn_mfma_f32_16x16x32_bf16(af, wf[ks], acc[mf], 0, 0, 0);
    }
  }

  {
    const int n = w * 16 + (lane & 15);
    const int side = n >> 5, o = n & 31;
    const float bias = side ? br[o] : bl[o];
    const float sc = side ? (1.0f / D) : 1.0f;
    unsigned short* dst = side ? rightT : leftT;
    #pragma unroll
    for (int mf = 0; mf < 4; ++mf) {
      const int rbase = mf * 16 + ((lane >> 4) << 2);
      const int ll = rbase >> 3, ddb = rbase & 7;
      unsigned short u[4];
      #pragma unroll
      for (int r = 0; r < 4; ++r) u[r] = f2bf((acc[mf][r] + bias) * sc);
      *(bhalf4*)(dst + ((size_t)(l0 + ll) * 32 + o) * 128 + d0 + ddb) = *(bhalf4*)u;
    }
  }
}

// ---------------- Kernel 2a: outer product -> Os (frag-packed, global) ----------------
// 2048 blocks (XCD-swizzled; tile 4l x 8m = 32 pairs), 512 thr = 8 waves (2x4).
// Os chunk (64 KB, at blockIdx.x): elem ((nf*32+ks)*64+lane)*8+j =
//   O[pair = nf*16+(lane&15)][k' = ks*32+(lane>>4)*8+j], pair = ll*8+mm local.
__global__ __launch_bounds__(512, 4)
void op_outer(const unsigned short* __restrict__ leftT,
              const unsigned short* __restrict__ rightT,
              unsigned short* __restrict__ OsG) {
  __shared__ char smem[65536];   // A0@0(16K), B@16384(32K), A1@49152(16K); then Os 64K

  const int flat = blockIdx.x;
  const int wg = (flat & 7) * 256 + (flat >> 3);   // bijective (2048 % 8 == 0)
  const int mt = wg & 31, lt = wg >> 5;
  const int l0 = lt * 4, m0 = mt * 8;

  const char* Aslab = (const char*)(leftT  + (size_t)l0 * 32 * 128);  // 128 rows x 256B
  const char* Bslab = (const char*)(rightT + (size_t)m0 * 32 * 128);  // 256 rows x 256B

  const int tid = threadIdx.x, lane = tid & 63, w = tid >> 6;
  const int wr = w >> 2, wc = w & 3;

  f32x4 acc[4][4];
  #pragma unroll
  for (int i = 0; i < 4; ++i)
    #pragma unroll
    for (int j = 0; j < 4; ++j) acc[i][j] = (f32x4)0.f;

  auto stageA = [&](int kh, int dst) {
    #pragma unroll
    for (int i = 0; i < 2; ++i) {
      const int lb = (i * 512 + tid) * 16;
      const int row = lb >> 7;
      const int sb = (lb & 127) ^ ((row & 7) << 4);
      __builtin_amdgcn_global_load_lds((const void*)(Aslab + (size_t)row * 256 + kh * 128 + sb),
                                       (void*)&smem[dst + lb], 16, 0, 0);
    }
  };
  auto stageB = [&](int kh) {
    #pragma unroll
    for (int i = 0; i < 4; ++i) {
      const int lb = (i * 512 + tid) * 16;
      const int row = lb >> 7;
      const int sb = (lb & 127) ^ ((row & 7) << 4);
      __builtin_amdgcn_global_load_lds((const void*)(Bslab + (size_t)row * 256 + kh * 128 + sb),
                                       (void*)&smem[16384 + lb], 16, 0, 0);
    }
  };
  auto computeKh = [&](int abase) {
    #pragma unroll
    for (int ks = 0; ks < 2; ++ks) {
      const int kb = ks * 64 + ((lane >> 4) << 4);
      bfrag8 a[4], b[4];
      #pragma unroll
      for (int i = 0; i < 4; ++i) {
        const int row = wr * 64 + i * 16 + (lane & 15);
        a[i] = *(const bfrag8*)&smem[abase + (row << 7) + (kb ^ ((row & 7) << 4))];
      }
      #pragma unroll
      for (int j = 0; j < 4; ++j) {
        const int row = wc * 64 + j * 16 + (lane & 15);
        b[j] = *(const bfrag8*)&smem[16384 + (row << 7) + (kb ^ ((row & 7) << 4))];
      }
      #pragma unroll
      for (int i = 0; i < 4; ++i)
        #pragma unroll
        for (int j = 0; j < 4; ++j)
          acc[i][j] = __builtin_amdgcn_mfma_f32_16x16x32_bf16(a[i], b[j], acc[i][j], 0, 0, 0);
    }
  };

  // ---- Phase 1 (r11 pattern) ----
  stageA(0, 0);
  stageB(0);
  __syncthreads();
  stageA(1, 49152);
  u32x4 b1r[4];
  #pragma unroll
  for (int i = 0; i < 4; ++i) {
    const int lb = (i * 512 + tid) * 16;
    const int row = lb >> 7;
    const int sb = (lb & 127) ^ ((row & 7) << 4);
    b1r[i] = *(const u32x4*)(Bslab + (size_t)row * 256 + 128 + sb);
  }
  computeKh(0);
  __syncthreads();
  #pragma unroll
  for (int i = 0; i < 4; ++i)
    *(u32x4*)&smem[16384 + (i * 512 + tid) * 16] = b1r[i];
  __syncthreads();
  computeKh(49152);
  __syncthreads();

  // ---- Phase 1.5: acc -> Os LDS [pair][k'=q*32+c], swizzle S=(pair&7)^((q>>1)&7) ----
  {
    #pragma unroll
    for (int i = 0; i < 4; ++i) {
      const int rowb = wr * 64 + i * 16 + ((lane >> 4) << 2);
      const int ll = rowb >> 5, cc = rowb & 31;
      #pragma unroll
      for (int j = 0; j < 4; ++j) {
        const int col = wc * 64 + j * 16 + (lane & 15);
        const int mm = col >> 5, q = col & 31;
        const int pair = ll * 8 + mm;                       // 0..31
        const int kp = q * 32 + cc;
        const int S = (pair & 7) ^ ((q >> 1) & 7);
        const int byte = pair * 2048 + ((kp * 2) ^ (S << 4));
        uint2 u;
        u.x = (unsigned)f2bf(acc[i][j][0]) | ((unsigned)f2bf(acc[i][j][1]) << 16);
        u.y = (unsigned)f2bf(acc[i][j][2]) | ((unsigned)f2bf(acc[i][j][3]) << 16);
        *(uint2*)&smem[byte] = u;
      }
    }
  }
  __syncthreads();

  // ---- pack: LDS (swizzled) -> global chunk in B-frag order; stores fully coalesced ----
  {
    char* dst = (char*)OsG + (size_t)flat * 65536;
    #pragma unroll
    for (int s = 0; s < 8; ++s) {
      const int e0 = (s * 512 + tid) * 8;          // elem index, 8 elems = 16B
      const int nf = e0 >> 14, ks = (e0 >> 9) & 31, l6 = (e0 >> 3) & 63;
      const int pair = nf * 16 + (l6 & 15);
      const int kpb = ks * 32 + ((l6 >> 4) << 3);
      const int S = (pair & 7) ^ ((kpb >> 6) & 7);
      const bfrag8 v = *(const bfrag8*)&smem[pair * 2048 + ((kpb * 2) ^ (S << 4))];
      *(bfrag8*)(dst + (size_t)e0 * 2) = v;
    }
  }
}

// ---------------- Kernel 2b: output projection (pure GEMM, no LDS, no barriers) ----------------
// 512 blocks x 512 thr = 8 waves (4 p-quarter x 2 pair-half). Block b: pairs of
// chunks 4b..4b+3 (128 pairs), all 256 p, K=1024. A = Wbf3 (L2-hot), B = OsG stream.
__global__ __launch_bounds__(512, 4)
void op_proj(const unsigned short* __restrict__ OsG,
             const unsigned short* __restrict__ Wbf3,
             const float* __restrict__ bout,
             float* __restrict__ out) {
  const int b = blockIdx.x;
  const int tid = threadIdx.x, lane = tid & 63, w = tid >> 6;
  const int wr = w >> 1, wc = w & 1;   // p-quarter (4 pf), pair-half (2 chunks)

  const unsigned short* afp = Wbf3 + (size_t)wr * 4 * 16384 + (size_t)lane * 8;
  const unsigned short* bfp = OsG + ((size_t)(4 * b + wc * 2)) * 32768 + (size_t)lane * 8;

  f32x4 acc[4][4];
  #pragma unroll
  for (int i = 0; i < 4; ++i)
    #pragma unroll
    for (int n = 0; n < 4; ++n) acc[i][n] = (f32x4)0.f;

  #pragma unroll 4
  for (int ks = 0; ks < 32; ++ks) {
    bfrag8 af[4], bf[4];
    #pragma unroll
    for (int i = 0; i < 4; ++i)
      af[i] = *(const bfrag8*)(afp + (size_t)i * 16384 + ks * 512);
    #pragma unroll
    for (int n = 0; n < 4; ++n)
      bf[n] = *(const bfrag8*)(bfp + (size_t)(n >> 1) * 32768 + (n & 1) * 16384 + ks * 512);
    #pragma unroll
    for (int i = 0; i < 4; ++i)
      #pragma unroll
      for (int n = 0; n < 4; ++n)
        acc[i][n] = __builtin_amdgcn_mfma_f32_16x16x32_bf16(af[i], bf[n], acc[i][n], 0, 0, 0);
  }

  // epilogue: row = p (regs), col = pair; decode chunk -> (l,m)
  #pragma unroll
  for (int n = 0; n < 4; ++n) {
    const int chunkFlat = 4 * b + wc * 2 + (n >> 1);
    const int cwg = (chunkFlat & 7) * 256 + (chunkFlat >> 3);
    const int mt = cwg & 31, lt = cwg >> 5;
    const int pairLoc = (n & 1) * 16 + (lane & 15);
    const int ll = pairLoc >> 3, mm = pairLoc & 7;
    const size_t rowbase = ((size_t)(lt * 4 + ll) * L + (mt * 8 + mm)) * PC;
    #pragma unroll
    for (int i = 0; i < 4; ++i) {
      const int p0 = (wr * 4 + i) * 16 + ((lane >> 4) << 2);
      const float4 bb = *(const float4*)&bout[p0];
      float4 v;
      v.x = acc[i][n][0] + bb.x;
      v.y = acc[i][n][1] + bb.y;
      v.z = acc[i][n][2] + bb.z;
      v.w = acc[i][n][3] + bb.w;
      *(float4*)&out[rowbase + p0] = v;
    }
  }
}

// ---------------- Fallback: r11 fused kernel (used when ws too small for Os) ----------------
__global__ __launch_bounds__(512, 4)
void fused_mfma(const unsigned short* __restrict__ leftT,
                const unsigned short* __restrict__ rightT,
                const unsigned short* __restrict__ Wbf3,
                const float* __restrict__ bout,
                float* __restrict__ out) {
  __shared__ char smem[65536];

  const int flat = blockIdx.x;
  const int wg = (flat & 7) * 256 + (flat >> 3);
  const int mt = wg & 31, lt = wg >> 5;
  const int l0 = lt * 4, m0 = mt * 8;

  const char* Aslab = (const char*)(leftT  + (size_t)l0 * 32 * 128);
  const char* Bslab = (const char*)(rightT + (size_t)m0 * 32 * 128);

  const int tid = threadIdx.x, lane = tid & 63, w = tid >> 6;
  const int wr = w >> 2, wc = w & 3;

  f32x4 acc[4][4];
  #pragma unroll
  for (int i = 0; i < 4; ++i)
    #pragma unroll
    for (int j = 0; j < 4; ++j) acc[i][j] = (f32x4)0.f;

  auto stageA = [&](int kh, int dst) {
    #pragma unroll
    for (int i = 0; i < 2; ++i) {
      const int lb = (i * 512 + tid) * 16;
      const int row = lb >> 7;
      const int sb = (lb & 127) ^ ((row & 7) << 4);
      __builtin_amdgcn_global_load_lds((const void*)(Aslab + (size_t)row * 256 + kh * 128 + sb),
                                       (void*)&smem[dst + lb], 16, 0, 0);
    }
  };
  auto stageB = [&](int kh) {
    #pragma unroll
    for (int i = 0; i < 4; ++i) {
      const int lb = (i * 512 + tid) * 16;
      const int row = lb >> 7;
      const int sb = (lb & 127) ^ ((row & 7) << 4);
      __builtin_amdgcn_global_load_lds((const void*)(Bslab + (size_t)row * 256 + kh * 128 + sb),
                                       (void*)&smem[16384 + lb], 16, 0, 0);
    }
  };
  auto computeKh = [&](int abase) {
    #pragma unroll
    for (int ks = 0; ks < 2; ++ks) {
      const int kb = ks * 64 + ((lane >> 4) << 4);
      bfrag8 a[4], b[4];
      #pragma unroll
      for (int i = 0; i < 4; ++i) {
        const int row = wr * 64 + i * 16 + (lane & 15);
        a[i] = *(const bfrag8*)&smem[abase + (row << 7) + (kb ^ ((row & 7) << 4))];
      }
      #pragma unroll
      for (int j = 0; j < 4; ++j) {
        const int row = wc * 64 + j * 16 + (lane & 15);
        b[j] = *(const bfrag8*)&smem[16384 + (row << 7) + (kb ^ ((row & 7) << 4))];
      }
      #pragma unroll
      for (int i = 0; i < 4; ++i)
        #pragma unroll
        for (int j = 0; j < 4; ++j)
          acc[i][j] = __builtin_amdgcn_mfma_f32_16x16x32_bf16(a[i], b[j], acc[i][j], 0, 0, 0);
    }
  };

  stageA(0, 0);
  stageB(0);
  __syncthreads();
  stageA(1, 49152);
  u32x4 b1r[4];
  #pragma unroll
  for (int i = 0; i < 4; ++i) {
    const int lb = (i * 512 + tid) * 16;
    const int row = lb >> 7;
    const int sb = (lb & 127) ^ ((row & 7) << 4);
    b1r[i] = *(const u32x4*)(Bslab + (size_t)row * 256 + 128 + sb);
  }
  computeKh(0);
  __syncthreads();
  #pragma unroll
  for (int i = 0; i < 4; ++i)
    *(u32x4*)&smem[16384 + (i * 512 + tid) * 16] = b1r[i];
  __syncthreads();
  computeKh(49152);
  __syncthreads();

  {
    #pragma unroll
    for (int i = 0; i < 4; ++i) {
      const int rowb = wr * 64 + i * 16 + ((lane >> 4) << 2);
      const int ll = rowb >> 5, cc = rowb & 31;
      #pragma unroll
      for (int j = 0; j < 4; ++j) {
        const int col = wc * 64 + j * 16 + (lane & 15);
        const int mm = col >> 5, q = col & 31;
        const int pair = ll * 8 + mm;
        const int kp = q * 32 + cc;
        const int S = (pair & 7) ^ ((q >> 1) & 7);
        const int byte = pair * 2048 + ((kp * 2) ^ (S << 4));
        uint2 u;
        u.x = (unsigned)f2bf(acc[i][j][0]) | ((unsigned)f2bf(acc[i][j][1]) << 16);
        u.y = (unsigned)f2bf(acc[i][j][2]) | ((unsigned)f2bf(acc[i][j][3]) << 16);
        *(uint2*)&smem[byte] = u;
      }
    }
  }

  const unsigned short* wp0 = Wbf3 + (((size_t)(w * 2)     * 32) * 64 + lane) * 8;
  const unsigned short* wp1 = Wbf3 + (((size_t)(w * 2 + 1) * 32) * 64 + lane) * 8;

  bfrag8 wfs[4][2];
  #pragma unroll
  for (int s = 0; s < 4; ++s) {
    wfs[s][0] = *(const bfrag8*)(wp0 + s * 512);
    wfs[s][1] = *(const bfrag8*)(wp1 + s * 512);
  }
  __syncthreads();

  f32x4 oacc[2][2];
  #pragma unroll
  for (int u = 0; u < 2; ++u)
    #pragma unroll
    for (int pj = 0; pj < 2; ++pj) oacc[u][pj] = (f32x4)0.f;

  auto ldos = [&](int ks, bfrag8* o) {
    #pragma unroll
    for (int pj = 0; pj < 2; ++pj) {
      const int pair = pj * 16 + (lane & 15);
      const int S = (pair & 7) ^ ((ks >> 1) & 7);
      o[pj] = *(const bfrag8*)&smem[pair * 2048 + ((ks * 64 + ((lane >> 4) << 4)) ^ (S << 4))];
    }
  };

  bfrag8 osA[2], osB[2];
  ldos(0, osA);

  #pragma unroll
  for (int ks = 0; ks < 32; ks += 2) {
    ldos(ks + 1, osB);
    __builtin_amdgcn_s_setprio(1);
    oacc[0][0] = __builtin_amdgcn_mfma_f32_16x16x32_bf16(wfs[ks & 3][0], osA[0], oacc[0][0], 0, 0, 0);
    oacc[0][1] = __builtin_amdgcn_mfma_f32_16x16x32_bf16(wfs[ks & 3][0], osA[1], oacc[0][1], 0, 0, 0);
    oacc[1][0] = __builtin_amdgcn_mfma_f32_16x16x32_bf16(wfs[ks & 3][1], osA[0], oacc[1][0], 0, 0, 0);
    oacc[1][1] = __builtin_amdgcn_mfma_f32_16x16x32_bf16(wfs[ks & 3][1], osA[1], oacc[1][1], 0, 0, 0);
    __builtin_amdgcn_s_setprio(0);
    if (ks + 4 < 32) {
      wfs[ks & 3][0] = *(const bfrag8*)(wp0 + (ks + 4) * 512);
      wfs[ks & 3][1] = *(const bfrag8*)(wp1 + (ks + 4) * 512);
    }
    if (ks + 2 < 32) ldos(ks + 2, osA);
    __builtin_amdgcn_s_setprio(1);
    oacc[0][0] = __builtin_amdgcn_mfma_f32_16x16x32_bf16(wfs[(ks + 1) & 3][0], osB[0], oacc[0][0], 0, 0, 0);
    oacc[0][1] = __builtin_amdgcn_mfma_f32_16x16x32_bf16(wfs[(ks + 1) & 3][0], osB[1], oacc[0][1], 0, 0, 0);
    oacc[1][0] = __builtin_amdgcn_mfma_f32_16x16x32_bf16(wfs[(ks + 1) & 3][1], osB[0], oacc[1][0], 0, 0, 0);
    oacc[1][1] = __builtin_amdgcn_mfma_f32_16x16x32_bf16(wfs[(ks + 1) & 3][1], osB[1], oacc[1][1], 0, 0, 0);
    __builtin_amdgcn_s_setprio(0);
    if (ks + 5 < 32) {
      wfs[(ks + 1) & 3][0] = *(const bfrag8*)(wp0 + (ks + 5) * 512);
      wfs[(ks + 1) & 3][1] = *(const bfrag8*)(wp1 + (ks + 5) * 512);
    }
  }

  {
    #pragma unroll
    for (int u = 0; u < 2; ++u) {
      const int p0 = (w * 2 + u) * 16 + ((lane >> 4) << 2);
      const float4 bb = *(const float4*)&bout[p0];
      #pragma unroll
      for (int pj = 0; pj < 2; ++pj) {
        const int pair = pj * 16 + (lane & 15);
        const int ll = pair >> 3, mm = pair & 7;
        float4 v;
        v.x = oacc[u][pj][0] + bb.x;
        v.y = oacc[u][pj][1] + bb.y;
        v.z = oacc[u][pj][2] + bb.z;
        v.w = oacc[u][pj][3] + bb.w;
        *(float4*)&out[((size_t)(l0 + ll) * L + (m0 + mm)) * PC + p0] = v;
      }
    }
  }
}

extern "C" void kernel_launch(void* const* d_in, const int* in_sizes, int n_in,
                              void* d_out, int out_size, void* d_ws, size_t ws_size,
                              hipStream_t stream) {
  const float* msa  = (const float*)d_in[0];
  const float* ln_w = (const float*)d_in[1];
  const float* ln_b = (const float*)d_in[2];
  const float* Wl   = (const float*)d_in[3];
  const float* bl   = (const float*)d_in[4];
  const float* Wr   = (const float*)d_in[5];
  const float* br   = (const float*)d_in[6];
  const float* Wout = (const float*)d_in[7];
  const float* bout = (const float*)d_in[8];
  float* out = (float*)d_out;

  unsigned short* leftT  = (unsigned short*)d_ws;                 // 2 MB
  unsigned short* rightT = leftT + (size_t)L * 32 * 128;          // 2 MB
  unsigned short* Wbf3   = rightT + (size_t)L * 32 * 128;         // 512 KB
  unsigned short* Wlnf   = Wbf3 + (size_t)PC * 1024;              // 32 KB
  unsigned short* OsG    = Wlnf + 16384;                          // 134.2 MB (split path)

  const size_t ws_needed = ((char*)(OsG + (size_t)2048 * 32768) - (char*)d_ws);

  prep<<<dim3(256), 256, 0, stream>>>(Wl, Wr, Wout, Wbf3, Wlnf);
  ln_proj<<<dim3(16, 32), 256, 0, stream>>>(msa, ln_w, ln_b, Wlnf, bl, br, leftT, rightT);
  if (ws_size >= ws_needed) {
    op_outer<<<dim3(2048), 512, 0, stream>>>(leftT, rightT, OsG);
    op_proj<<<dim3(512), 512, 0, stream>>>(OsG, Wbf3, bout, out);
  } else {
    fused_mfma<<<dim3(2048), 512, 0, stream>>>(leftT, rightT, Wbf3, bout, out);
  }
}

// Round 13
// 83.293 us; speedup vs baseline: 1.3505x; 1.3505x over previous
//
#include <hip/hip_runtime.h>

#define EPS 1e-5f

static constexpr int D  = 128;
static constexpr int L  = 256;
static constexpr int C  = 256;
static constexpr int OC = 32;
static constexpr int PC = 256;

typedef __attribute__((ext_vector_type(8))) short bfrag8;   // 8 bf16 (4 VGPR)
typedef __attribute__((ext_vector_type(4))) short bhalf4;   // 4 bf16 (8B)
typedef __attribute__((ext_vector_type(4))) float f32x4;
typedef __attribute__((ext_vector_type(4))) unsigned int u32x4;

__device__ inline unsigned short f2bf(float f) {
  union { float f; unsigned u; } v; v.f = f;
  unsigned r = v.u + 0x7FFF + ((v.u >> 16) & 1);   // RNE
  return (unsigned short)(r >> 16);
}

// ---------------- Kernel 1: prep (blocks 0..63) + LayerNorm/projection (blocks 64..575) ----
// prep part: Wbf3 = Wout bf16 in MFMA A-frag order (M-side = p):
//   elem ((pf*32+ks)*64+lane)*8+j = Wout[p = pf*16+(lane&15)][orig(kp)],
//   kp = ks*32+(lane>>4)*8+j; kp = q*32+c -> orig = c*32+q.
// ln part: block = 8 d x 8 l rows; weight frags built inline from Wl/Wr (L2-hot).
__global__ __launch_bounds__(256, 4)
void prep_ln(const float* __restrict__ msa,
             const float* __restrict__ lnw, const float* __restrict__ lnb,
             const float* __restrict__ Wl, const float* __restrict__ Wr,
             const float* __restrict__ Wout,
             const float* __restrict__ bl, const float* __restrict__ br,
             unsigned short* __restrict__ Wbf3,
             unsigned short* __restrict__ leftT, unsigned short* __restrict__ rightT) {
  const int t = threadIdx.x;
  const int b = blockIdx.x;

  if (b < 64) {   // ---- Wbf3 frag-pack: 64 blocks x 256 thr x 16 elems ----
    #pragma unroll
    for (int j2 = 0; j2 < 4; ++j2) {
      const int e0 = (b * 256 + t) * 16 + j2 * 4;
      const int lane = (e0 >> 3) & 63, ks = (e0 >> 9) & 31, pf = e0 >> 14;
      const int p = pf * 16 + (lane & 15);
      unsigned short v[4];
      #pragma unroll
      for (int j = 0; j < 4; ++j) {
        const int kp = ks * 32 + ((lane >> 4) * 8) + ((e0 + j) & 7);
        const int c = kp & 31, q = kp >> 5;
        v[j] = f2bf(Wout[p * 1024 + c * 32 + q]);
      }
      *(bhalf4*)(Wbf3 + e0) = *(bhalf4*)v;
    }
    return;
  }

  // ---- ln_proj part ----
  __shared__ char xb[32768];   // [64 r][256 c] bf16, swizzled ^((r&7)<<4)

  const int bb = b - 64;
  const int lane = t & 63, w = t >> 6;
  const int d0 = (bb & 15) * 8, l0 = (bb >> 4) * 8;

  float4 xv[16];
  #pragma unroll
  for (int i = 0; i < 16; ++i) {
    const int r = i * 4 + w, dd = r & 7, ll = r >> 3;
    xv[i] = *(const float4*)(msa + ((size_t)(d0 + dd) * 256 + (l0 + ll)) * 256 + lane * 4);
  }

  // build weight frags inline (replaces Wlnf): n = w*16+(lane&15)
  bfrag8 wf[8];
  {
    const int n = w * 16 + (lane & 15);
    const int side = n >> 5, o = n & 31;
    const float* Wrow = (side ? Wr : Wl) + o * 256 + ((lane >> 4) * 8);
    #pragma unroll
    for (int ks = 0; ks < 8; ++ks) {
      const float4 w0 = *(const float4*)(Wrow + ks * 32);
      const float4 w1 = *(const float4*)(Wrow + ks * 32 + 4);
      unsigned short u[8];
      u[0] = f2bf(w0.x); u[1] = f2bf(w0.y); u[2] = f2bf(w0.z); u[3] = f2bf(w0.w);
      u[4] = f2bf(w1.x); u[5] = f2bf(w1.y); u[6] = f2bf(w1.z); u[7] = f2bf(w1.w);
      wf[ks] = *(bfrag8*)u;
    }
  }

  float mu[16], rs[16];
  #pragma unroll
  for (int i = 0; i < 16; ++i) {
    float s  = xv[i].x + xv[i].y + xv[i].z + xv[i].w;
    float s2 = xv[i].x * xv[i].x + xv[i].y * xv[i].y + xv[i].z * xv[i].z + xv[i].w * xv[i].w;
    #pragma unroll
    for (int off = 32; off >= 1; off >>= 1) {
      s  += __shfl_xor(s, off);
      s2 += __shfl_xor(s2, off);
    }
    mu[i] = s * (1.0f / C);
    rs[i] = rsqrtf(s2 * (1.0f / C) - mu[i] * mu[i] + EPS);
  }

  {
    const float4 wv = *(const float4*)(lnw + lane * 4);
    const float4 bv = *(const float4*)(lnb + lane * 4);
    #pragma unroll
    for (int i = 0; i < 16; ++i) {
      const int r = i * 4 + w;
      float4 v = xv[i];
      unsigned short u[4];
      u[0] = f2bf((v.x - mu[i]) * rs[i] * wv.x + bv.x);
      u[1] = f2bf((v.y - mu[i]) * rs[i] * wv.y + bv.y);
      u[2] = f2bf((v.z - mu[i]) * rs[i] * wv.z + bv.z);
      u[3] = f2bf((v.w - mu[i]) * rs[i] * wv.w + bv.w);
      *(bhalf4*)&xb[r * 512 + ((lane * 8) ^ ((r & 7) << 4))] = *(bhalf4*)u;
    }
  }
  __syncthreads();

  f32x4 acc[4];
  #pragma unroll
  for (int mf = 0; mf < 4; ++mf) acc[mf] = (f32x4)0.f;
  #pragma unroll
  for (int ks = 0; ks < 8; ++ks) {
    #pragma unroll
    for (int mf = 0; mf < 4; ++mf) {
      const int row = mf * 16 + (lane & 15);
      const bfrag8 af = *(const bfrag8*)&xb[row * 512 +
                          ((ks * 64 + ((lane >> 4) << 4)) ^ ((row & 7) << 4))];
      acc[mf] = __builtin_amdgcn_mfma_f32_16x16x32_bf16(af, wf[ks], acc[mf], 0, 0, 0);
    }
  }

  {
    const int n = w * 16 + (lane & 15);
    const int side = n >> 5, o = n & 31;
    const float bias = side ? br[o] : bl[o];
    const float sc = side ? (1.0f / D) : 1.0f;
    unsigned short* dst = side ? rightT : leftT;
    #pragma unroll
    for (int mf = 0; mf < 4; ++mf) {
      const int rbase = mf * 16 + ((lane >> 4) << 2);
      const int ll = rbase >> 3, ddb = rbase & 7;
      unsigned short u[4];
      #pragma unroll
      for (int r = 0; r < 4; ++r) u[r] = f2bf((acc[mf][r] + bias) * sc);
      *(bhalf4*)(dst + ((size_t)(l0 + ll) * 32 + o) * 128 + d0 + ddb) = *(bhalf4*)u;
    }
  }
}

// ---------------- Kernel 2: fused outer-product + output projection (r11 structure) --------
// 2048 blocks (XCD-swizzled; tile 4l x 8m = 32 pairs), 512 thr = 8 waves (2x4).
// Phase 1: A1 tail-prefetch (gload_lds) + B1 reg-staged (T14). Phase 2: osA/osB
// depth-1 LDS pipeline + depth-4 wfs ring + setprio (no barriers in phase 2).
__global__ __launch_bounds__(512, 4)
void fused_mfma(const unsigned short* __restrict__ leftT,
                const unsigned short* __restrict__ rightT,
                const unsigned short* __restrict__ Wbf3,
                const float* __restrict__ bout,
                float* __restrict__ out) {
  __shared__ char smem[65536];   // ph1: A0@0(16K), B@16384(32K), A1@49152(16K); ph2: Os 64K

  const int flat = blockIdx.x;
  const int wg = (flat & 7) * 256 + (flat >> 3);   // bijective (2048 % 8 == 0)
  const int mt = wg & 31, lt = wg >> 5;            // 64 l-tiles x 32 m-tiles
  const int l0 = lt * 4, m0 = mt * 8;

  const char* Aslab = (const char*)(leftT  + (size_t)l0 * 32 * 128);  // 128 rows x 256B
  const char* Bslab = (const char*)(rightT + (size_t)m0 * 32 * 128);  // 256 rows x 256B

  const int tid = threadIdx.x, lane = tid & 63, w = tid >> 6;
  const int wr = w >> 2, wc = w & 3;   // wave tile 64x64 of O (128 rows x 256 cols)

  f32x4 acc[4][4];
  #pragma unroll
  for (int i = 0; i < 4; ++i)
    #pragma unroll
    for (int j = 0; j < 4; ++j) acc[i][j] = (f32x4)0.f;

  auto stageA = [&](int kh, int dst) {
    #pragma unroll
    for (int i = 0; i < 2; ++i) {     // 16KB
      const int lb = (i * 512 + tid) * 16;
      const int row = lb >> 7;
      const int sb = (lb & 127) ^ ((row & 7) << 4);
      __builtin_amdgcn_global_load_lds((const void*)(Aslab + (size_t)row * 256 + kh * 128 + sb),
                                       (void*)&smem[dst + lb], 16, 0, 0);
    }
  };
  auto stageB = [&](int kh) {
    #pragma unroll
    for (int i = 0; i < 4; ++i) {     // 32KB @16384
      const int lb = (i * 512 + tid) * 16;
      const int row = lb >> 7;
      const int sb = (lb & 127) ^ ((row & 7) << 4);
      __builtin_amdgcn_global_load_lds((const void*)(Bslab + (size_t)row * 256 + kh * 128 + sb),
                                       (void*)&smem[16384 + lb], 16, 0, 0);
    }
  };
  auto computeKh = [&](int abase) {
    #pragma unroll
    for (int ks = 0; ks < 2; ++ks) {
      const int kb = ks * 64 + ((lane >> 4) << 4);
      bfrag8 a[4], b[4];
      #pragma unroll
      for (int i = 0; i < 4; ++i) {
        const int row = wr * 64 + i * 16 + (lane & 15);
        a[i] = *(const bfrag8*)&smem[abase + (row << 7) + (kb ^ ((row & 7) << 4))];
      }
      #pragma unroll
      for (int j = 0; j < 4; ++j) {
        const int row = wc * 64 + j * 16 + (lane & 15);
        b[j] = *(const bfrag8*)&smem[16384 + (row << 7) + (kb ^ ((row & 7) << 4))];
      }
      #pragma unroll
      for (int i = 0; i < 4; ++i)
        #pragma unroll
        for (int j = 0; j < 4; ++j)
          acc[i][j] = __builtin_amdgcn_mfma_f32_16x16x32_bf16(a[i], b[j], acc[i][j], 0, 0, 0);
    }
  };

  // ---- Phase 1 ----
  stageA(0, 0);
  stageB(0);
  __syncthreads();
  stageA(1, 49152);              // gload_lds into free tail; overlaps kh0 compute
  u32x4 b1r[4];                  // T14: B1 -> registers, in flight under kh0 compute
  #pragma unroll
  for (int i = 0; i < 4; ++i) {
    const int lb = (i * 512 + tid) * 16;
    const int row = lb >> 7;
    const int sb = (lb & 127) ^ ((row & 7) << 4);
    b1r[i] = *(const u32x4*)(Bslab + (size_t)row * 256 + 128 + sb);
  }
  computeKh(0);
  __syncthreads();               // B0 reads done; A1 + b1r arrived
  #pragma unroll
  for (int i = 0; i < 4; ++i)    // B1 regs -> LDS (same linear layout)
    *(u32x4*)&smem[16384 + (i * 512 + tid) * 16] = b1r[i];
  __syncthreads();               // B1 visible
  computeKh(49152);
  __syncthreads();               // all phase-1 reads done before Os writes

  // ---- Phase 1.5: acc -> Os[pair 0..31][k'=q*32+c], swizzle S=(pair&7)^((q>>1)&7) ----
  {
    #pragma unroll
    for (int i = 0; i < 4; ++i) {
      const int rowb = wr * 64 + i * 16 + ((lane >> 4) << 2);
      const int ll = rowb >> 5, cc = rowb & 31;
      #pragma unroll
      for (int j = 0; j < 4; ++j) {
        const int col = wc * 64 + j * 16 + (lane & 15);
        const int mm = col >> 5, q = col & 31;
        const int pair = ll * 8 + mm;                       // 0..31
        const int kp = q * 32 + cc;
        const int S = (pair & 7) ^ ((q >> 1) & 7);
        const int byte = pair * 2048 + ((kp * 2) ^ (S << 4));
        uint2 u;
        u.x = (unsigned)f2bf(acc[i][j][0]) | ((unsigned)f2bf(acc[i][j][1]) << 16);
        u.y = (unsigned)f2bf(acc[i][j][2]) | ((unsigned)f2bf(acc[i][j][3]) << 16);
        *(uint2*)&smem[byte] = u;
      }
    }
  }

  // ---- Phase 2 prologue: depth-4 wf prefetch hoisted ABOVE the Os barrier ----
  const unsigned short* wp0 = Wbf3 + (((size_t)(w * 2)     * 32) * 64 + lane) * 8;
  const unsigned short* wp1 = Wbf3 + (((size_t)(w * 2 + 1) * 32) * 64 + lane) * 8;

  bfrag8 wfs[4][2];
  #pragma unroll
  for (int s = 0; s < 4; ++s) {
    wfs[s][0] = *(const bfrag8*)(wp0 + s * 512);
    wfs[s][1] = *(const bfrag8*)(wp1 + s * 512);
  }
  __syncthreads();   // Os ready (wf loads already in flight)

  // ---- Phase 2: OUT[256 p][32 pairs], K=1024; osA/osB depth-1 + wfs ring ----
  f32x4 oacc[2][2];
  #pragma unroll
  for (int u = 0; u < 2; ++u)
    #pragma unroll
    for (int pj = 0; pj < 2; ++pj) oacc[u][pj] = (f32x4)0.f;

  auto ldos = [&](int ks, bfrag8* o) {
    #pragma unroll
    for (int pj = 0; pj < 2; ++pj) {
      const int pair = pj * 16 + (lane & 15);
      const int S = (pair & 7) ^ ((ks >> 1) & 7);
      o[pj] = *(const bfrag8*)&smem[pair * 2048 + ((ks * 64 + ((lane >> 4) << 4)) ^ (S << 4))];
    }
  };

  bfrag8 osA[2], osB[2];
  ldos(0, osA);

  #pragma unroll
  for (int ks = 0; ks < 32; ks += 2) {
    ldos(ks + 1, osB);
    __builtin_amdgcn_s_setprio(1);
    oacc[0][0] = __builtin_amdgcn_mfma_f32_16x16x32_bf16(wfs[ks & 3][0], osA[0], oacc[0][0], 0, 0, 0);
    oacc[0][1] = __builtin_amdgcn_mfma_f32_16x16x32_bf16(wfs[ks & 3][0], osA[1], oacc[0][1], 0, 0, 0);
    oacc[1][0] = __builtin_amdgcn_mfma_f32_16x16x32_bf16(wfs[ks & 3][1], osA[0], oacc[1][0], 0, 0, 0);
    oacc[1][1] = __builtin_amdgcn_mfma_f32_16x16x32_bf16(wfs[ks & 3][1], osA[1], oacc[1][1], 0, 0, 0);
    __builtin_amdgcn_s_setprio(0);
    if (ks + 4 < 32) {             // refill consumed slot (compile-time)
      wfs[ks & 3][0] = *(const bfrag8*)(wp0 + (ks + 4) * 512);
      wfs[ks & 3][1] = *(const bfrag8*)(wp1 + (ks + 4) * 512);
    }
    if (ks + 2 < 32) ldos(ks + 2, osA);
    __builtin_amdgcn_s_setprio(1);
    oacc[0][0] = __builtin_amdgcn_mfma_f32_16x16x32_bf16(wfs[(ks + 1) & 3][0], osB[0], oacc[0][0], 0, 0, 0);
    oacc[0][1] = __builtin_amdgcn_mfma_f32_16x16x32_bf16(wfs[(ks + 1) & 3][0], osB[1], oacc[0][1], 0, 0, 0);
    oacc[1][0] = __builtin_amdgcn_mfma_f32_16x16x32_bf16(wfs[(ks + 1) & 3][1], osB[0], oacc[1][0], 0, 0, 0);
    oacc[1][1] = __builtin_amdgcn_mfma_f32_16x16x32_bf16(wfs[(ks + 1) & 3][1], osB[1], oacc[1][1], 0, 0, 0);
    __builtin_amdgcn_s_setprio(0);
    if (ks + 5 < 32) {
      wfs[(ks + 1) & 3][0] = *(const bfrag8*)(wp0 + (ks + 5) * 512);
      wfs[(ks + 1) & 3][1] = *(const bfrag8*)(wp1 + (ks + 5) * 512);
    }
  }

  // ---- epilogue: row = p (regs), col = pair ----
  {
    #pragma unroll
    for (int u = 0; u < 2; ++u) {
      const int p0 = (w * 2 + u) * 16 + ((lane >> 4) << 2);
      const float4 bb = *(const float4*)&bout[p0];
      #pragma unroll
      for (int pj = 0; pj < 2; ++pj) {
        const int pair = pj * 16 + (lane & 15);
        const int ll = pair >> 3, mm = pair & 7;
        float4 v;
        v.x = oacc[u][pj][0] + bb.x;
        v.y = oacc[u][pj][1] + bb.y;
        v.z = oacc[u][pj][2] + bb.z;
        v.w = oacc[u][pj][3] + bb.w;
        *(float4*)&out[((size_t)(l0 + ll) * L + (m0 + mm)) * PC + p0] = v;
      }
    }
  }
}

extern "C" void kernel_launch(void* const* d_in, const int* in_sizes, int n_in,
                              void* d_out, int out_size, void* d_ws, size_t ws_size,
                              hipStream_t stream) {
  const float* msa  = (const float*)d_in[0];
  const float* ln_w = (const float*)d_in[1];
  const float* ln_b = (const float*)d_in[2];
  const float* Wl   = (const float*)d_in[3];
  const float* bl   = (const float*)d_in[4];
  const float* Wr   = (const float*)d_in[5];
  const float* br   = (const float*)d_in[6];
  const float* Wout = (const float*)d_in[7];
  const float* bout = (const float*)d_in[8];
  float* out = (float*)d_out;

  unsigned short* leftT  = (unsigned short*)d_ws;                 // [L*32][128] bf16 = 2 MB
  unsigned short* rightT = leftT + (size_t)L * 32 * 128;          // 2 MB
  unsigned short* Wbf3   = rightT + (size_t)L * 32 * 128;         // 512 KB (frag-packed)

  prep_ln<<<dim3(576), 256, 0, stream>>>(msa, ln_w, ln_b, Wl, Wr, Wout, bl, br,
                                         Wbf3, leftT, rightT);
  fused_mfma<<<dim3(2048), 512, 0, stream>>>(leftT, rightT, Wbf3, bout, out);
}

// Round 14
// 81.818 us; speedup vs baseline: 1.3749x; 1.0180x over previous
//
#include <hip/hip_runtime.h>

#define EPS 1e-5f

static constexpr int D  = 128;
static constexpr int L  = 256;
static constexpr int C  = 256;
static constexpr int OC = 32;
static constexpr int PC = 256;

typedef __attribute__((ext_vector_type(8))) short bfrag8;   // 8 bf16 (4 VGPR)
typedef __attribute__((ext_vector_type(4))) short bhalf4;   // 4 bf16 (8B)
typedef __attribute__((ext_vector_type(4))) float f32x4;
typedef __attribute__((ext_vector_type(4))) unsigned int u32x4;

__device__ inline unsigned short f2bf(float f) {
  union { float f; unsigned u; } v; v.f = f;
  unsigned r = v.u + 0x7FFF + ((v.u >> 16) & 1);   // RNE
  return (unsigned short)(r >> 16);
}

// ---------------- Kernel 1: prep (blocks 0..63) + LayerNorm/projection (blocks 64..575) ----
// prep part: Wbf3 = Wout bf16 in MFMA A-frag order (M-side = p), k''-ordered:
//   k'' = q*32 + c2*8 + hi*4 + r  <->  cc = hi*16 + c2*4 + r; orig = cc*32 + q.
//   elem ((pf*32+ks)*64+lane)*8+jj = Wout[p = pf*16+(lane&15)][orig(k'')],
//   k'' = ks*32 + (lane>>4)*8 + jj.
// ln part: block = 8 d x 8 l rows; weight frags built inline from Wl/Wr (L2-hot).
__global__ __launch_bounds__(256, 4)
void prep_ln(const float* __restrict__ msa,
             const float* __restrict__ lnw, const float* __restrict__ lnb,
             const float* __restrict__ Wl, const float* __restrict__ Wr,
             const float* __restrict__ Wout,
             const float* __restrict__ bl, const float* __restrict__ br,
             unsigned short* __restrict__ Wbf3,
             unsigned short* __restrict__ leftT, unsigned short* __restrict__ rightT) {
  const int t = threadIdx.x;
  const int b = blockIdx.x;

  if (b < 64) {   // ---- Wbf3 frag-pack: 64 blocks x 256 thr x 16 elems ----
    #pragma unroll
    for (int j2 = 0; j2 < 4; ++j2) {
      const int e0 = (b * 256 + t) * 16 + j2 * 4;
      const int lane = (e0 >> 3) & 63, ks = (e0 >> 9) & 31, pf = e0 >> 14;
      const int p = pf * 16 + (lane & 15);
      unsigned short v[4];
      #pragma unroll
      for (int j = 0; j < 4; ++j) {
        const int kp = ks * 32 + ((lane >> 4) * 8) + ((e0 + j) & 7);   // k''
        const int q = kp >> 5, t5 = kp & 31;
        const int cc = ((t5 >> 2) & 1) * 16 + (t5 >> 3) * 4 + (t5 & 3);
        v[j] = f2bf(Wout[p * 1024 + cc * 32 + q]);
      }
      *(bhalf4*)(Wbf3 + e0) = *(bhalf4*)v;
    }
    return;
  }

  // ---- ln_proj part ----
  __shared__ char xb[32768];   // [64 r][256 c] bf16, swizzled ^((r&7)<<4)

  const int bb = b - 64;
  const int lane = t & 63, w = t >> 6;
  const int d0 = (bb & 15) * 8, l0 = (bb >> 4) * 8;

  float4 xv[16];
  #pragma unroll
  for (int i = 0; i < 16; ++i) {
    const int r = i * 4 + w, dd = r & 7, ll = r >> 3;
    xv[i] = *(const float4*)(msa + ((size_t)(d0 + dd) * 256 + (l0 + ll)) * 256 + lane * 4);
  }

  // build weight frags inline: n = w*16+(lane&15)
  bfrag8 wf[8];
  {
    const int n = w * 16 + (lane & 15);
    const int side = n >> 5, o = n & 31;
    const float* Wrow = (side ? Wr : Wl) + o * 256 + ((lane >> 4) * 8);
    #pragma unroll
    for (int ks = 0; ks < 8; ++ks) {
      const float4 w0 = *(const float4*)(Wrow + ks * 32);
      const float4 w1 = *(const float4*)(Wrow + ks * 32 + 4);
      unsigned short u[8];
      u[0] = f2bf(w0.x); u[1] = f2bf(w0.y); u[2] = f2bf(w0.z); u[3] = f2bf(w0.w);
      u[4] = f2bf(w1.x); u[5] = f2bf(w1.y); u[6] = f2bf(w1.z); u[7] = f2bf(w1.w);
      wf[ks] = *(bfrag8*)u;
    }
  }

  float mu[16], rs[16];
  #pragma unroll
  for (int i = 0; i < 16; ++i) {
    float s  = xv[i].x + xv[i].y + xv[i].z + xv[i].w;
    float s2 = xv[i].x * xv[i].x + xv[i].y * xv[i].y + xv[i].z * xv[i].z + xv[i].w * xv[i].w;
    #pragma unroll
    for (int off = 32; off >= 1; off >>= 1) {
      s  += __shfl_xor(s, off);
      s2 += __shfl_xor(s2, off);
    }
    mu[i] = s * (1.0f / C);
    rs[i] = rsqrtf(s2 * (1.0f / C) - mu[i] * mu[i] + EPS);
  }

  {
    const float4 wv = *(const float4*)(lnw + lane * 4);
    const float4 bv = *(const float4*)(lnb + lane * 4);
    #pragma unroll
    for (int i = 0; i < 16; ++i) {
      const int r = i * 4 + w;
      float4 v = xv[i];
      unsigned short u[4];
      u[0] = f2bf((v.x - mu[i]) * rs[i] * wv.x + bv.x);
      u[1] = f2bf((v.y - mu[i]) * rs[i] * wv.y + bv.y);
      u[2] = f2bf((v.z - mu[i]) * rs[i] * wv.z + bv.z);
      u[3] = f2bf((v.w - mu[i]) * rs[i] * wv.w + bv.w);
      *(bhalf4*)&xb[r * 512 + ((lane * 8) ^ ((r & 7) << 4))] = *(bhalf4*)u;
    }
  }
  __syncthreads();

  f32x4 acc[4];
  #pragma unroll
  for (int mf = 0; mf < 4; ++mf) acc[mf] = (f32x4)0.f;
  #pragma unroll
  for (int ks = 0; ks < 8; ++ks) {
    #pragma unroll
    for (int mf = 0; mf < 4; ++mf) {
      const int row = mf * 16 + (lane & 15);
      const bfrag8 af = *(const bfrag8*)&xb[row * 512 +
                          ((ks * 64 + ((lane >> 4) << 4)) ^ ((row & 7) << 4))];
      acc[mf] = __builtin_amdgcn_mfma_f32_16x16x32_bf16(af, wf[ks], acc[mf], 0, 0, 0);
    }
  }

  {
    const int n = w * 16 + (lane & 15);
    const int side = n >> 5, o = n & 31;
    const float bias = side ? br[o] : bl[o];
    const float sc = side ? (1.0f / D) : 1.0f;
    unsigned short* dst = side ? rightT : leftT;
    #pragma unroll
    for (int mf = 0; mf < 4; ++mf) {
      const int rbase = mf * 16 + ((lane >> 4) << 2);
      const int ll = rbase >> 3, ddb = rbase & 7;
      unsigned short u[4];
      #pragma unroll
      for (int r = 0; r < 4; ++r) u[r] = f2bf((acc[mf][r] + bias) * sc);
      *(bhalf4*)(dst + ((size_t)(l0 + ll) * 32 + o) * 128 + d0 + ddb) = *(bhalf4*)u;
    }
  }
}

// ---------------- Kernel 2: fused outer-product + output projection --------
// 2048 blocks (XCD-swizzled; tile 4l x 8m = 32 pairs), 512 thr = 8 waves (2x4).
// Phase 1: A1 tail-prefetch (gload_lds) + B1 reg-staged (T14).
// Phase 1.5: b128 Os stores (hi-halves packed; k''-order).
// Phase 2: osf ring depth 3 + wfs ring depth 4 + setprio.
__global__ __launch_bounds__(512, 4)
void fused_mfma(const unsigned short* __restrict__ leftT,
                const unsigned short* __restrict__ rightT,
                const unsigned short* __restrict__ Wbf3,
                const float* __restrict__ bout,
                float* __restrict__ out) {
  __shared__ char smem[65536];   // ph1: A0@0(16K), B@16384(32K), A1@49152(16K); ph2: Os 64K

  const int flat = blockIdx.x;
  const int wg = (flat & 7) * 256 + (flat >> 3);   // bijective (2048 % 8 == 0)
  const int mt = wg & 31, lt = wg >> 5;            // 64 l-tiles x 32 m-tiles
  const int l0 = lt * 4, m0 = mt * 8;

  const char* Aslab = (const char*)(leftT  + (size_t)l0 * 32 * 128);  // 128 rows x 256B
  const char* Bslab = (const char*)(rightT + (size_t)m0 * 32 * 128);  // 256 rows x 256B

  const int tid = threadIdx.x, lane = tid & 63, w = tid >> 6;
  const int wr = w >> 2, wc = w & 3;   // wave tile 64x64 of O (128 rows x 256 cols)

  f32x4 acc[4][4];
  #pragma unroll
  for (int i = 0; i < 4; ++i)
    #pragma unroll
    for (int j = 0; j < 4; ++j) acc[i][j] = (f32x4)0.f;

  auto stageA = [&](int kh, int dst) {
    #pragma unroll
    for (int i = 0; i < 2; ++i) {     // 16KB
      const int lb = (i * 512 + tid) * 16;
      const int row = lb >> 7;
      const int sb = (lb & 127) ^ ((row & 7) << 4);
      __builtin_amdgcn_global_load_lds((const void*)(Aslab + (size_t)row * 256 + kh * 128 + sb),
                                       (void*)&smem[dst + lb], 16, 0, 0);
    }
  };
  auto stageB = [&](int kh) {
    #pragma unroll
    for (int i = 0; i < 4; ++i) {     // 32KB @16384
      const int lb = (i * 512 + tid) * 16;
      const int row = lb >> 7;
      const int sb = (lb & 127) ^ ((row & 7) << 4);
      __builtin_amdgcn_global_load_lds((const void*)(Bslab + (size_t)row * 256 + kh * 128 + sb),
                                       (void*)&smem[16384 + lb], 16, 0, 0);
    }
  };
  auto computeKh = [&](int abase) {
    #pragma unroll
    for (int ks = 0; ks < 2; ++ks) {
      const int kb = ks * 64 + ((lane >> 4) << 4);
      bfrag8 a[4], b[4];
      #pragma unroll
      for (int i = 0; i < 4; ++i) {
        const int row = wr * 64 + i * 16 + (lane & 15);
        a[i] = *(const bfrag8*)&smem[abase + (row << 7) + (kb ^ ((row & 7) << 4))];
      }
      #pragma unroll
      for (int j = 0; j < 4; ++j) {
        const int row = wc * 64 + j * 16 + (lane & 15);
        b[j] = *(const bfrag8*)&smem[16384 + (row << 7) + (kb ^ ((row & 7) << 4))];
      }
      #pragma unroll
      for (int i = 0; i < 4; ++i)
        #pragma unroll
        for (int j = 0; j < 4; ++j)
          acc[i][j] = __builtin_amdgcn_mfma_f32_16x16x32_bf16(a[i], b[j], acc[i][j], 0, 0, 0);
    }
  };

  // ---- Phase 1 ----
  stageA(0, 0);
  stageB(0);
  __syncthreads();
  stageA(1, 49152);              // gload_lds into free tail; overlaps kh0 compute
  u32x4 b1r[4];                  // T14: B1 -> registers, in flight under kh0 compute
  #pragma unroll
  for (int i = 0; i < 4; ++i) {
    const int lb = (i * 512 + tid) * 16;
    const int row = lb >> 7;
    const int sb = (lb & 127) ^ ((row & 7) << 4);
    b1r[i] = *(const u32x4*)(Bslab + (size_t)row * 256 + 128 + sb);
  }
  computeKh(0);
  __syncthreads();               // B0 reads done; A1 + b1r arrived
  #pragma unroll
  for (int i = 0; i < 4; ++i)    // B1 regs -> LDS (same linear layout)
    *(u32x4*)&smem[16384 + (i * 512 + tid) * 16] = b1r[i];
  __syncthreads();               // B1 visible
  computeKh(49152);
  __syncthreads();               // all phase-1 reads done before Os writes

  // ---- Phase 1.5: acc -> Os[pair][k''] via b128 stores (hi-halves packed) ----
  // k'' = q*32 + c2*8 + hi*4 + r; granule byte base = q*64 + c2*16, c2 = lane>>4.
  {
    const int c2_16 = (lane >> 4) << 4;
    #pragma unroll
    for (int ip = 0; ip < 2; ++ip) {          // i = 2*ip (hi=0), 2*ip+1 (hi=1); same ll
      const int ll = wr * 2 + ip;
      #pragma unroll
      for (int j = 0; j < 4; ++j) {
        const int col = wc * 64 + j * 16 + (lane & 15);
        const int mm = col >> 5, q = col & 31;
        const int pair = ll * 8 + mm;         // 0..31
        const int S = (pair & 7) ^ ((q >> 1) & 7);
        const int byte = pair * 2048 + ((q * 64 + c2_16) ^ (S << 4));
        u32x4 u;
        u[0] = (unsigned)f2bf(acc[2 * ip][j][0])     | ((unsigned)f2bf(acc[2 * ip][j][1]) << 16);
        u[1] = (unsigned)f2bf(acc[2 * ip][j][2])     | ((unsigned)f2bf(acc[2 * ip][j][3]) << 16);
        u[2] = (unsigned)f2bf(acc[2 * ip + 1][j][0]) | ((unsigned)f2bf(acc[2 * ip + 1][j][1]) << 16);
        u[3] = (unsigned)f2bf(acc[2 * ip + 1][j][2]) | ((unsigned)f2bf(acc[2 * ip + 1][j][3]) << 16);
        *(u32x4*)&smem[byte] = u;
      }
    }
  }

  // ---- Phase 2 prologue: depth-4 wf prefetch hoisted ABOVE the Os barrier ----
  const unsigned short* wp0 = Wbf3 + (((size_t)(w * 2)     * 32) * 64 + lane) * 8;
  const unsigned short* wp1 = Wbf3 + (((size_t)(w * 2 + 1) * 32) * 64 + lane) * 8;

  bfrag8 wfs[4][2];
  #pragma unroll
  for (int s = 0; s < 4; ++s) {
    wfs[s][0] = *(const bfrag8*)(wp0 + s * 512);
    wfs[s][1] = *(const bfrag8*)(wp1 + s * 512);
  }
  __syncthreads();   // Os ready (wf loads already in flight)

  // ---- Phase 2: OUT[256 p][32 pairs], K=1024; osf ring depth 3 + wfs ring ----
  f32x4 oacc[2][2];
  #pragma unroll
  for (int u = 0; u < 2; ++u)
    #pragma unroll
    for (int pj = 0; pj < 2; ++pj) oacc[u][pj] = (f32x4)0.f;

  auto ldos = [&](int ks, bfrag8* o) {
    #pragma unroll
    for (int pj = 0; pj < 2; ++pj) {
      const int pair = pj * 16 + (lane & 15);
      const int S = (pair & 7) ^ ((ks >> 1) & 7);
      o[pj] = *(const bfrag8*)&smem[pair * 2048 + ((ks * 64 + ((lane >> 4) << 4)) ^ (S << 4))];
    }
  };

  bfrag8 osf[4][2];
  ldos(0, osf[0]);
  ldos(1, osf[1]);
  ldos(2, osf[2]);

  #pragma unroll
  for (int ks = 0; ks < 32; ++ks) {
    if (ks + 3 < 32) ldos(ks + 3, osf[(ks + 3) & 3]);   // compile-time slot
    __builtin_amdgcn_s_setprio(1);
    oacc[0][0] = __builtin_amdgcn_mfma_f32_16x16x32_bf16(wfs[ks & 3][0], osf[ks & 3][0], oacc[0][0], 0, 0, 0);
    oacc[0][1] = __builtin_amdgcn_mfma_f32_16x16x32_bf16(wfs[ks & 3][0], osf[ks & 3][1], oacc[0][1], 0, 0, 0);
    oacc[1][0] = __builtin_amdgcn_mfma_f32_16x16x32_bf16(wfs[ks & 3][1], osf[ks & 3][0], oacc[1][0], 0, 0, 0);
    oacc[1][1] = __builtin_amdgcn_mfma_f32_16x16x32_bf16(wfs[ks & 3][1], osf[ks & 3][1], oacc[1][1], 0, 0, 0);
    __builtin_amdgcn_s_setprio(0);
    if (ks + 4 < 32) {                                   // refill consumed wf slot
      wfs[ks & 3][0] = *(const bfrag8*)(wp0 + (ks + 4) * 512);
      wfs[ks & 3][1] = *(const bfrag8*)(wp1 + (ks + 4) * 512);
    }
  }

  // ---- epilogue: row = p (regs), col = pair ----
  {
    #pragma unroll
    for (int u = 0; u < 2; ++u) {
      const int p0 = (w * 2 + u) * 16 + ((lane >> 4) << 2);
      const float4 bb = *(const float4*)&bout[p0];
      #pragma unroll
      for (int pj = 0; pj < 2; ++pj) {
        const int pair = pj * 16 + (lane & 15);
        const int ll = pair >> 3, mm = pair & 7;
        float4 v;
        v.x = oacc[u][pj][0] + bb.x;
        v.y = oacc[u][pj][1] + bb.y;
        v.z = oacc[u][pj][2] + bb.z;
        v.w = oacc[u][pj][3] + bb.w;
        *(float4*)&out[((size_t)(l0 + ll) * L + (m0 + mm)) * PC + p0] = v;
      }
    }
  }
}

extern "C" void kernel_launch(void* const* d_in, const int* in_sizes, int n_in,
                              void* d_out, int out_size, void* d_ws, size_t ws_size,
                              hipStream_t stream) {
  const float* msa  = (const float*)d_in[0];
  const float* ln_w = (const float*)d_in[1];
  const float* ln_b = (const float*)d_in[2];
  const float* Wl   = (const float*)d_in[3];
  const float* bl   = (const float*)d_in[4];
  const float* Wr   = (const float*)d_in[5];
  const float* br   = (const float*)d_in[6];
  const float* Wout = (const float*)d_in[7];
  const float* bout = (const float*)d_in[8];
  float* out = (float*)d_out;

  unsigned short* leftT  = (unsigned short*)d_ws;                 // [L*32][128] bf16 = 2 MB
  unsigned short* rightT = leftT + (size_t)L * 32 * 128;          // 2 MB
  unsigned short* Wbf3   = rightT + (size_t)L * 32 * 128;         // 512 KB (frag-packed)

  prep_ln<<<dim3(576), 256, 0, stream>>>(msa, ln_w, ln_b, Wl, Wr, Wout, bl, br,
                                         Wbf3, leftT, rightT);
  fused_mfma<<<dim3(2048), 512, 0, stream>>>(leftT, rightT, Wbf3, bout, out);
}